// Round 3
// baseline (166.346 us; speedup 1.0000x reference)
//
#include <hip/hip_runtime.h>

// out[i] = prod_j sigmoid((ub[j] - logit(bc[idx[i][j]])) / (ub[j] - lb[j] + 1e-4))
//
// HBM floor: 96 MiB idx read + 32 MiB out write ~= 20 us @ 6.3 TB/s.
// R1 (162 us, 4 rows/thread, 48-B lane stride) vs R2 (166 us, wave-coalesced
// + LDS transpose): structurally different VMEM/LDS patterns, identical time
// -> dur_us is dominated by an additive harness-reset constant (402-MB 0xAA
// fill = 59 us + ~96 MiB d_in restore per replay, visible in rocprof).
// R3: simplest minimal-issue structure — ONE row per thread:
//   int3 load (12 B/lane, 12 cachelines/wave — fewer TA ops than any 4-row
//   scheme), 3 random LDS gathers from a 3x1000 sigmoid LUT, scalar store.
// Per-CU issue ~13 us < 20 us HBM floor -> pure stream-bound kernel.

#define EPS 1e-4f
#define TPB 256
#define NBLK 2048
#define BINCAP 1024

__global__ __launch_bounds__(TPB) void pm_kernel(
    const float* __restrict__ bc,      // [nbins]
    const int*   __restrict__ idx,     // [ndiffs, 3] int32
    const float* __restrict__ lo,      // [3]
    const float* __restrict__ hi,      // [3]
    float*       __restrict__ out,     // [ndiffs]
    int nbins, int ndiffs)
{
    __shared__ float tab0[BINCAP];     // separate arrays: 3 independent
    __shared__ float tab1[BINCAP];     // random gathers per thread
    __shared__ float tab2[BINCAP];

    // Effective bounds (reference swaps if lb > ub)
    const float lb0 = fminf(lo[0], hi[0]), ub0 = fmaxf(lo[0], hi[0]);
    const float lb1 = fminf(lo[1], hi[1]), ub1 = fmaxf(lo[1], hi[1]);
    const float lb2 = fminf(lo[2], hi[2]), ub2 = fmaxf(lo[2], hi[2]);
    const float r0 = 1.0f / (ub0 - lb0 + EPS);
    const float r1 = 1.0f / (ub1 - lb1 + EPS);
    const float r2 = 1.0f / (ub2 - lb2 + EPS);

    // 3x1000 sigmoid LUT: transcendentals are O(bins), not O(rows).
    for (int b = threadIdx.x; b < nbins; b += TPB) {
        const float t = bc[b];
        const float g = __logf(t / (1.0f - t));          // logit
        tab0[b] = 1.0f / (1.0f + __expf((g - ub0) * r0));
        tab1[b] = 1.0f / (1.0f + __expf((g - ub1) * r1));
        tab2[b] = 1.0f / (1.0f + __expf((g - ub2) * r2));
    }
    __syncthreads();

    const int tid    = blockIdx.x * TPB + threadIdx.x;
    const int stride = NBLK * TPB;

    const int3* __restrict__ idx3 = (const int3*)idx;    // 12-B packed row

    for (int i = tid; i < ndiffs; i += stride) {
        const int3 v = idx3[i];                          // dwordx3, lane stride 12 B
        out[i] = tab0[v.x] * tab1[v.y] * tab2[v.z];
    }
}

extern "C" void kernel_launch(void* const* d_in, const int* in_sizes, int n_in,
                              void* d_out, int out_size, void* d_ws, size_t ws_size,
                              hipStream_t stream)
{
    const float* bc  = (const float*)d_in[0];   // bin_centers [nbins]
    const int*   idx = (const int*)  d_in[1];   // observation_probability_index [ndiffs*3]
    const float* lo  = (const float*)d_in[2];   // lower_bounds [3]
    const float* hi  = (const float*)d_in[3];   // upper_bounds [3]
    float*       out = (float*)d_out;

    pm_kernel<<<NBLK, TPB, 0, stream>>>(bc, idx, lo, hi, out, in_sizes[0], out_size);
}